// Round 4
// baseline (59.595 us; speedup 1.0000x reference)
//
#include <hip/hip_runtime.h>

#define D_FEAT 128

// Monotonic float -> uint map: preserves order, so uint atomicMin/Max == float min/max.
__device__ __forceinline__ unsigned mapf(float f) {
    unsigned u = __float_as_uint(f);
    return (u & 0x80000000u) ? ~u : (u | 0x80000000u);
}
__device__ __forceinline__ float unmapf(unsigned u) {
    return (u & 0x80000000u) ? __uint_as_float(u & 0x7FFFFFFFu)
                             : __uint_as_float(~u);
}

// K1: per-node projection, 8-lane group per node (32 nodes / 256-thread block).
// Thread (group g, sublane t) reads h[node][j*32 + t*4 .. +3] for j=0..3:
// four independent float4 loads = 64 B/lane in flight; reduce = 3 shuffle rounds.
__global__ __launch_bounds__(256) void proj_kernel(
    const float* __restrict__ h,
    const float* __restrict__ W,
    float* __restrict__ pu,
    float* __restrict__ pv,
    unsigned* __restrict__ g,
    int n_nodes)
{
    if (blockIdx.x == 0 && threadIdx.x == 0) { g[0] = 0xFFFFFFFFu; g[1] = 0u; }

    const int t    = threadIdx.x & 7;           // sublane within 8-lane group
    const int node = blockIdx.x * 32 + (threadIdx.x >> 3);
    if (node >= n_nodes) return;                 // whole 8-lane group exits together

    const float4* W4 = (const float4*)W;         // W[0:128]=Wu, W[128:256]=Wv
    float4 wu[4], wv[4];
    #pragma unroll
    for (int j = 0; j < 4; ++j) {
        wu[j] = W4[j * 8 + t];                   // L1-resident after first wave
        wv[j] = W4[32 + j * 8 + t];
    }

    const float4* h4 = (const float4*)(h + (size_t)node * D_FEAT);
    float4 hv[4];
    #pragma unroll
    for (int j = 0; j < 4; ++j) hv[j] = h4[j * 8 + t];   // 4 independent loads

    float su = 0.f, sv = 0.f;
    #pragma unroll
    for (int j = 0; j < 4; ++j) {
        su += hv[j].x*wu[j].x + hv[j].y*wu[j].y + hv[j].z*wu[j].z + hv[j].w*wu[j].w;
        sv += hv[j].x*wv[j].x + hv[j].y*wv[j].y + hv[j].z*wv[j].z + hv[j].w*wv[j].w;
    }
    #pragma unroll
    for (int off = 4; off > 0; off >>= 1) {      // xor 4,2,1: stays within 8-lane group
        su += __shfl_xor(su, off, 64);
        sv += __shfl_xor(sv, off, 64);
    }
    if (t == 0) { pu[node] = su; pv[node] = sv; }   // 8 consecutive nodes/wave: 32B store
}

// K2: 8 edges/thread; raw scores -> out; per-wave min/max -> 2 atomics per wave.
__global__ __launch_bounds__(256) void score_kernel(
    const int*   __restrict__ src,
    const int*   __restrict__ dst,
    const float* __restrict__ pu,
    const float* __restrict__ pv,
    const float* __restrict__ bptr,
    float*       __restrict__ out,
    unsigned*    __restrict__ g,
    int n_edges)
{
    const int i  = blockIdx.x * blockDim.x + threadIdx.x;
    const int e0 = i * 8;
    float vmin =  3.4028235e38f;
    float vmax = -3.4028235e38f;
    const float bb = bptr[0];

    if (e0 + 8 <= n_edges) {
        const int4 s0 = ((const int4*)src)[i * 2];
        const int4 s1 = ((const int4*)src)[i * 2 + 1];
        const int4 d0 = ((const int4*)dst)[i * 2];
        const int4 d1 = ((const int4*)dst)[i * 2 + 1];
        float4 o0, o1;                           // 16 independent gathers in flight
        o0.x = pu[s0.x] + pv[d0.x] + bb;
        o0.y = pu[s0.y] + pv[d0.y] + bb;
        o0.z = pu[s0.z] + pv[d0.z] + bb;
        o0.w = pu[s0.w] + pv[d0.w] + bb;
        o1.x = pu[s1.x] + pv[d1.x] + bb;
        o1.y = pu[s1.y] + pv[d1.y] + bb;
        o1.z = pu[s1.z] + pv[d1.z] + bb;
        o1.w = pu[s1.w] + pv[d1.w] + bb;
        ((float4*)out)[i * 2]     = o0;
        ((float4*)out)[i * 2 + 1] = o1;
        vmin = fminf(fminf(fminf(o0.x, o0.y), fminf(o0.z, o0.w)),
                     fminf(fminf(o1.x, o1.y), fminf(o1.z, o1.w)));
        vmax = fmaxf(fmaxf(fmaxf(o0.x, o0.y), fmaxf(o0.z, o0.w)),
                     fmaxf(fmaxf(o1.x, o1.y), fmaxf(o1.z, o1.w)));
    } else if (e0 < n_edges) {
        for (int e = e0; e < n_edges; ++e) {
            const float s = pu[src[e]] + pv[dst[e]] + bb;
            out[e] = s;
            vmin = fminf(vmin, s);
            vmax = fmaxf(vmax, s);
        }
    }

    #pragma unroll
    for (int off = 32; off > 0; off >>= 1) {
        vmin = fminf(vmin, __shfl_xor(vmin, off, 64));
        vmax = fmaxf(vmax, __shfl_xor(vmax, off, 64));
    }
    if ((threadIdx.x & 63) == 0) {               // one pair of atomics per wave
        atomicMin(&g[0], mapf(vmin));
        atomicMax(&g[1], mapf(vmax));
    }
}

// K3: in-place normalize, 8 edges/thread.
__global__ __launch_bounds__(256) void norm_kernel(
    float* __restrict__ out,
    const unsigned* __restrict__ g,
    int n_edges)
{
    const int i  = blockIdx.x * blockDim.x + threadIdx.x;
    const int e0 = i * 8;
    if (e0 >= n_edges) return;
    const float mn  = unmapf(g[0]);
    const float inv = 1.0f / (unmapf(g[1]) - mn);

    if (e0 + 8 <= n_edges) {
        float4 v0 = ((const float4*)out)[i * 2];
        float4 v1 = ((const float4*)out)[i * 2 + 1];
        v0.x = (v0.x - mn) * inv;  v0.y = (v0.y - mn) * inv;
        v0.z = (v0.z - mn) * inv;  v0.w = (v0.w - mn) * inv;
        v1.x = (v1.x - mn) * inv;  v1.y = (v1.y - mn) * inv;
        v1.z = (v1.z - mn) * inv;  v1.w = (v1.w - mn) * inv;
        ((float4*)out)[i * 2]     = v0;
        ((float4*)out)[i * 2 + 1] = v1;
    } else {
        for (int e = e0; e < n_edges; ++e)
            out[e] = (out[e] - mn) * inv;
    }
}

extern "C" void kernel_launch(void* const* d_in, const int* in_sizes, int n_in,
                              void* d_out, int out_size, void* d_ws, size_t ws_size,
                              hipStream_t stream) {
    const float* h   = (const float*)d_in[0];
    const int*   src = (const int*)d_in[1];
    const int*   dst = (const int*)d_in[2];
    const float* W   = (const float*)d_in[3];
    const float* b   = (const float*)d_in[4];
    float* out = (float*)d_out;

    const int n_nodes = in_sizes[0] / D_FEAT;
    const int n_edges = in_sizes[1];

    // workspace: pu[n_nodes], pv[n_nodes], g[2] (uint)
    float* ws = (float*)d_ws;
    float* pu = ws;
    float* pv = ws + n_nodes;
    unsigned* g = (unsigned*)(ws + 2 * n_nodes);

    // K1: 32 nodes / 256-thread block
    {
        const int blocks = (n_nodes + 31) / 32;          // 3125 for 100K nodes
        proj_kernel<<<blocks, 256, 0, stream>>>(h, W, pu, pv, g, n_nodes);
    }
    // K2: 8 edges/thread
    {
        const int blocks = (n_edges + 2047) / 2048;      // 391 for 800K edges
        score_kernel<<<blocks, 256, 0, stream>>>(src, dst, pu, pv, b, out, g, n_edges);
    }
    // K3: 8 edges/thread, in-place
    {
        const int blocks = (n_edges + 2047) / 2048;
        norm_kernel<<<blocks, 256, 0, stream>>>(out, g, n_edges);
    }
}

// Round 5
// 41.947 us; speedup vs baseline: 1.4207x; 1.4207x over previous
//
#include <hip/hip_runtime.h>

#define D_FEAT 128

// Monotonic float -> uint map: preserves order, so uint atomicMin/Max == float min/max.
__device__ __forceinline__ unsigned mapf(float f) {
    unsigned u = __float_as_uint(f);
    return (u & 0x80000000u) ? ~u : (u | 0x80000000u);
}
__device__ __forceinline__ float unmapf(unsigned u) {
    return (u & 0x80000000u) ? __uint_as_float(u & 0x7FFFFFFFu)
                             : __uint_as_float(~u);
}

// g[0] = min cell, g[16] = max cell (separate 64B cache lines to decouple
// the two atomic serialization chains).
#define G_MIN 0
#define G_MAX 16

// K1: per-node projection, 8-lane group per node (32 nodes / 256-thread block).
// Four independent float4 loads = 64 B/lane in flight; reduce = 3 shuffle rounds.
__global__ __launch_bounds__(256) void proj_kernel(
    const float* __restrict__ h,
    const float* __restrict__ W,
    float* __restrict__ pu,
    float* __restrict__ pv,
    unsigned* __restrict__ g,
    int n_nodes)
{
    if (blockIdx.x == 0 && threadIdx.x == 0) { g[G_MIN] = 0xFFFFFFFFu; g[G_MAX] = 0u; }

    const int t    = threadIdx.x & 7;
    const int node = blockIdx.x * 32 + (threadIdx.x >> 3);
    if (node >= n_nodes) return;

    const float4* W4 = (const float4*)W;
    float4 wu[4], wv[4];
    #pragma unroll
    for (int j = 0; j < 4; ++j) {
        wu[j] = W4[j * 8 + t];
        wv[j] = W4[32 + j * 8 + t];
    }

    const float4* h4 = (const float4*)(h + (size_t)node * D_FEAT);
    float4 hv[4];
    #pragma unroll
    for (int j = 0; j < 4; ++j) hv[j] = h4[j * 8 + t];

    float su = 0.f, sv = 0.f;
    #pragma unroll
    for (int j = 0; j < 4; ++j) {
        su += hv[j].x*wu[j].x + hv[j].y*wu[j].y + hv[j].z*wu[j].z + hv[j].w*wu[j].w;
        sv += hv[j].x*wv[j].x + hv[j].y*wv[j].y + hv[j].z*wv[j].z + hv[j].w*wv[j].w;
    }
    #pragma unroll
    for (int off = 4; off > 0; off >>= 1) {
        su += __shfl_xor(su, off, 64);
        sv += __shfl_xor(sv, off, 64);
    }
    if (t == 0) { pu[node] = su; pv[node] = sv; }
}

// K2: 2 edges/thread (int2 index loads). High TLP is the point: 1563 blocks
// (~6 blocks/CU, ~24 waves/CU) to hide uncoalesced L2 gather latency.
__global__ __launch_bounds__(256) void score_kernel(
    const int*   __restrict__ src,
    const int*   __restrict__ dst,
    const float* __restrict__ pu,
    const float* __restrict__ pv,
    const float* __restrict__ bptr,
    float*       __restrict__ out,
    unsigned*    __restrict__ g,
    int n_edges)
{
    const int i  = blockIdx.x * blockDim.x + threadIdx.x;
    const int e0 = i * 2;
    float vmin =  3.4028235e38f;
    float vmax = -3.4028235e38f;
    const float bb = bptr[0];

    if (e0 + 2 <= n_edges) {
        const int2 s2 = ((const int2*)src)[i];
        const int2 d2 = ((const int2*)dst)[i];
        float2 o;
        o.x = pu[s2.x] + pv[d2.x] + bb;
        o.y = pu[s2.y] + pv[d2.y] + bb;
        ((float2*)out)[i] = o;
        vmin = fminf(o.x, o.y);
        vmax = fmaxf(o.x, o.y);
    } else if (e0 < n_edges) {
        const float s = pu[src[e0]] + pv[dst[e0]] + bb;
        out[e0] = s;
        vmin = s;
        vmax = s;
    }

    #pragma unroll
    for (int off = 32; off > 0; off >>= 1) {
        vmin = fminf(vmin, __shfl_xor(vmin, off, 64));
        vmax = fmaxf(vmax, __shfl_xor(vmax, off, 64));
    }
    __shared__ float smin[4], smax[4];
    const int w = threadIdx.x >> 6;
    if ((threadIdx.x & 63) == 0) { smin[w] = vmin; smax[w] = vmax; }
    __syncthreads();
    if (threadIdx.x == 0) {
        const float a = fminf(fminf(smin[0], smin[1]), fminf(smin[2], smin[3]));
        const float m = fmaxf(fmaxf(smax[0], smax[1]), fmaxf(smax[2], smax[3]));
        atomicMin(&g[G_MIN], mapf(a));
        atomicMax(&g[G_MAX], mapf(m));
    }
}

// K3: in-place normalize, 8 edges/thread (float4 x2 RMW).
__global__ __launch_bounds__(256) void norm_kernel(
    float* __restrict__ out,
    const unsigned* __restrict__ g,
    int n_edges)
{
    const int i  = blockIdx.x * blockDim.x + threadIdx.x;
    const int e0 = i * 8;
    if (e0 >= n_edges) return;
    const float mn  = unmapf(g[G_MIN]);
    const float inv = 1.0f / (unmapf(g[G_MAX]) - mn);

    if (e0 + 8 <= n_edges) {
        float4 v0 = ((const float4*)out)[i * 2];
        float4 v1 = ((const float4*)out)[i * 2 + 1];
        v0.x = (v0.x - mn) * inv;  v0.y = (v0.y - mn) * inv;
        v0.z = (v0.z - mn) * inv;  v0.w = (v0.w - mn) * inv;
        v1.x = (v1.x - mn) * inv;  v1.y = (v1.y - mn) * inv;
        v1.z = (v1.z - mn) * inv;  v1.w = (v1.w - mn) * inv;
        ((float4*)out)[i * 2]     = v0;
        ((float4*)out)[i * 2 + 1] = v1;
    } else {
        for (int e = e0; e < n_edges; ++e)
            out[e] = (out[e] - mn) * inv;
    }
}

extern "C" void kernel_launch(void* const* d_in, const int* in_sizes, int n_in,
                              void* d_out, int out_size, void* d_ws, size_t ws_size,
                              hipStream_t stream) {
    const float* h   = (const float*)d_in[0];
    const int*   src = (const int*)d_in[1];
    const int*   dst = (const int*)d_in[2];
    const float* W   = (const float*)d_in[3];
    const float* b   = (const float*)d_in[4];
    float* out = (float*)d_out;

    const int n_nodes = in_sizes[0] / D_FEAT;
    const int n_edges = in_sizes[1];

    // workspace: pu[n_nodes], pv[n_nodes], g[32] (uint; min at +0, max at +16)
    float* ws = (float*)d_ws;
    float* pu = ws;
    float* pv = ws + n_nodes;
    unsigned* g = (unsigned*)(ws + 2 * n_nodes);

    // K1: 32 nodes / 256-thread block
    {
        const int blocks = (n_nodes + 31) / 32;          // 3125
        proj_kernel<<<blocks, 256, 0, stream>>>(h, W, pu, pv, g, n_nodes);
    }
    // K2: 2 edges/thread -> 1563 blocks (~24 waves/CU)
    {
        const int blocks = (n_edges + 511) / 512;        // 1563
        score_kernel<<<blocks, 256, 0, stream>>>(src, dst, pu, pv, b, out, g, n_edges);
    }
    // K3: 8 edges/thread
    {
        const int blocks = (n_edges + 2047) / 2048;      // 391
        norm_kernel<<<blocks, 256, 0, stream>>>(out, g, n_edges);
    }
}

// Round 6
// 28.952 us; speedup vs baseline: 2.0584x; 1.4488x over previous
//
#include <hip/hip_runtime.h>

#define D_FEAT 128

// K1: per-node projection, 8-lane group per node (32 nodes / 256-thread block).
// pu[n] = h[n].Wu + b ; pv[n] = h[n].Wv
// Four independent float4 loads = 64 B/lane in flight; reduce = 3 shuffle rounds.
__global__ __launch_bounds__(256) void proj_kernel(
    const float* __restrict__ h,
    const float* __restrict__ W,
    const float* __restrict__ bptr,
    float* __restrict__ pu,
    float* __restrict__ pv,
    int n_nodes)
{
    const int t    = threadIdx.x & 7;
    const int node = blockIdx.x * 32 + (threadIdx.x >> 3);
    if (node >= n_nodes) return;

    const float4* W4 = (const float4*)W;
    float4 wu[4], wv[4];
    #pragma unroll
    for (int j = 0; j < 4; ++j) {
        wu[j] = W4[j * 8 + t];          // L1-resident after first wave
        wv[j] = W4[32 + j * 8 + t];
    }

    const float4* h4 = (const float4*)(h + (size_t)node * D_FEAT);
    float4 hv[4];
    #pragma unroll
    for (int j = 0; j < 4; ++j) hv[j] = h4[j * 8 + t];

    float su = 0.f, sv = 0.f;
    #pragma unroll
    for (int j = 0; j < 4; ++j) {
        su += hv[j].x*wu[j].x + hv[j].y*wu[j].y + hv[j].z*wu[j].z + hv[j].w*wu[j].w;
        sv += hv[j].x*wv[j].x + hv[j].y*wv[j].y + hv[j].z*wv[j].z + hv[j].w*wv[j].w;
    }
    #pragma unroll
    for (int off = 4; off > 0; off >>= 1) {   // xor 4,2,1: stays in 8-lane group
        su += __shfl_xor(su, off, 64);
        sv += __shfl_xor(sv, off, 64);
    }
    if (t == 0) {
        pu[node] = su + bptr[0];   // fold bias into pu: score = pu[src]+pv[dst]
        pv[node] = sv;
    }
}

// K2: 1 edge/thread, 3125 blocks (max TLP). Raw score -> out.
// Per-block min/max partials to DISTINCT addresses — no global atomics.
__global__ __launch_bounds__(256) void score_kernel(
    const int*   __restrict__ src,
    const int*   __restrict__ dst,
    const float* __restrict__ pu,
    const float* __restrict__ pv,
    float*       __restrict__ out,
    float*       __restrict__ pmin,
    float*       __restrict__ pmax,
    int n_edges)
{
    const int i = blockIdx.x * blockDim.x + threadIdx.x;
    float vmin =  3.4028235e38f;
    float vmax = -3.4028235e38f;
    if (i < n_edges) {
        const float s = pu[src[i]] + pv[dst[i]];   // pu/pv: 800 KB, L2-resident
        out[i] = s;
        vmin = s;
        vmax = s;
    }
    #pragma unroll
    for (int off = 32; off > 0; off >>= 1) {
        vmin = fminf(vmin, __shfl_xor(vmin, off, 64));
        vmax = fmaxf(vmax, __shfl_xor(vmax, off, 64));
    }
    __shared__ float smin[4], smax[4];
    const int w = threadIdx.x >> 6;
    if ((threadIdx.x & 63) == 0) { smin[w] = vmin; smax[w] = vmax; }
    __syncthreads();
    if (threadIdx.x == 0) {
        pmin[blockIdx.x] = fminf(fminf(smin[0], smin[1]), fminf(smin[2], smin[3]));
        pmax[blockIdx.x] = fmaxf(fmaxf(smax[0], smax[1]), fmaxf(smax[2], smax[3]));
    }
}

// K3: one 1024-thread block reduces the 3125 partial pairs -> g[0]=min, g[1]=max.
__global__ __launch_bounds__(1024) void minmax_reduce_kernel(
    const float* __restrict__ pmin,
    const float* __restrict__ pmax,
    float* __restrict__ g,
    int n)
{
    float vmin =  3.4028235e38f;
    float vmax = -3.4028235e38f;
    for (int i = threadIdx.x; i < n; i += 1024) {
        vmin = fminf(vmin, pmin[i]);
        vmax = fmaxf(vmax, pmax[i]);
    }
    #pragma unroll
    for (int off = 32; off > 0; off >>= 1) {
        vmin = fminf(vmin, __shfl_xor(vmin, off, 64));
        vmax = fmaxf(vmax, __shfl_xor(vmax, off, 64));
    }
    __shared__ float smin[16], smax[16];
    const int w = threadIdx.x >> 6;
    if ((threadIdx.x & 63) == 0) { smin[w] = vmin; smax[w] = vmax; }
    __syncthreads();
    if (threadIdx.x == 0) {
        float a = smin[0], m = smax[0];
        #pragma unroll
        for (int k = 1; k < 16; ++k) { a = fminf(a, smin[k]); m = fmaxf(m, smax[k]); }
        g[0] = a;
        g[1] = m;
    }
}

// K4: in-place normalize, float4, 1 vec4/thread (782 blocks).
__global__ __launch_bounds__(256) void norm_kernel(
    float* __restrict__ out,
    const float* __restrict__ g,
    int n4, int n_edges)
{
    const int i = blockIdx.x * blockDim.x + threadIdx.x;
    if (i >= n4) return;
    const float mn  = g[0];
    const float inv = 1.0f / (g[1] - mn);
    float4 v = ((const float4*)out)[i];
    v.x = (v.x - mn) * inv;
    v.y = (v.y - mn) * inv;
    v.z = (v.z - mn) * inv;
    v.w = (v.w - mn) * inv;
    ((float4*)out)[i] = v;
    if (i == n4 - 1) {
        for (int e = n4 * 4; e < n_edges; ++e)
            out[e] = (out[e] - mn) * inv;
    }
}

extern "C" void kernel_launch(void* const* d_in, const int* in_sizes, int n_in,
                              void* d_out, int out_size, void* d_ws, size_t ws_size,
                              hipStream_t stream) {
    const float* h   = (const float*)d_in[0];
    const int*   src = (const int*)d_in[1];
    const int*   dst = (const int*)d_in[2];
    const float* W   = (const float*)d_in[3];
    const float* b   = (const float*)d_in[4];
    float* out = (float*)d_out;

    const int n_nodes = in_sizes[0] / D_FEAT;
    const int n_edges = in_sizes[1];

    const int blk2 = (n_edges + 255) / 256;    // 3125

    // workspace: pu[n_nodes], pv[n_nodes], pmin[blk2], pmax[blk2], g[2]
    float* ws   = (float*)d_ws;
    float* pu   = ws;
    float* pv   = ws + n_nodes;
    float* pmin = ws + 2 * n_nodes;
    float* pmax = pmin + blk2;
    float* g    = pmax + blk2;

    // K1: 32 nodes / block -> 3125 blocks
    {
        const int blocks = (n_nodes + 31) / 32;
        proj_kernel<<<blocks, 256, 0, stream>>>(h, W, b, pu, pv, n_nodes);
    }
    // K2: 1 edge/thread -> 3125 blocks, no atomics
    score_kernel<<<blk2, 256, 0, stream>>>(src, dst, pu, pv, out, pmin, pmax, n_edges);
    // K3: single-block reduce of partials
    minmax_reduce_kernel<<<1, 1024, 0, stream>>>(pmin, pmax, g, blk2);
    // K4: normalize in place
    {
        const int n4 = n_edges >> 2;
        const int blocks = (n4 + 255) / 256;
        norm_kernel<<<blocks, 256, 0, stream>>>(out, g, n4, n_edges);
    }
}